// Round 13
// baseline (560.469 us; speedup 1.0000x reference)
//
#include <hip/hip_runtime.h>

#define N_P 50000
#define N_HE 5000
#define N_E 800000
#define D_IN 128
#define D_HID 256
#define N_HEADS 4
#define HEAD_DIM 64
#define CAP_HE 320
#define CAP_P  64
#define NTILE_TOT 3125   // 50000 / 16
#define NCHUNK1 782      // ceil(3125 / 4) chunks of 64 rows  (k_mlp1)
#define NCHUNK2 1563     // ceil(3125 / 2) chunks of 32 rows  (k_mlp23)
#define CS2 264          // LDS stride (shorts) for h1

typedef __attribute__((ext_vector_type(8))) short short8;
typedef __attribute__((ext_vector_type(4))) float f32x4;

__device__ __forceinline__ short f2bs(float x) {   // fp32 -> bf16 bits (RNE)
    union { float f; unsigned u; } v; v.f = x;
    unsigned r = (v.u + 0x7FFFu + ((v.u >> 16) & 1u)) >> 16;
    return (short)r;
}
__device__ __forceinline__ float bs2f(short s) {
    union { unsigned u; float f; } v; v.u = ((unsigned)(unsigned short)s) << 16;
    return v.f;
}

__global__ void k_zero_int(int* __restrict__ p, unsigned n) {
    unsigned i = blockIdx.x * blockDim.x + threadIdx.x;
    unsigned stride = gridDim.x * blockDim.x;
    for (; i < n; i += stride) p[i] = 0;
}

// ---------------- weight prep: fp32 -> split bf16 (hi+lo), transposed WT[n][k] ----------------
__global__ void k_prep(
    const float* __restrict__ Wself, const float* __restrict__ Wclu,
    const float* __restrict__ Wf1,   const float* __restrict__ Wf2,
    short* __restrict__ WselfT_hi, short* __restrict__ WselfT_lo,
    short* __restrict__ WcluT_hi,  short* __restrict__ WcluT_lo,
    short* __restrict__ Wf1T_hi,   short* __restrict__ Wf1T_lo,
    short* __restrict__ Wf2T_hi,   short* __restrict__ Wf2T_lo) {
    unsigned i = blockIdx.x * 256u + threadIdx.x;   // 512*256 = 131072 exact
    float v; short *hi, *lo; unsigned idx;
    if (i < 16384u) {
        unsigned j = i >> 7, d = i & 127u;
        v = Wself[d * 128 + j]; hi = WselfT_hi; lo = WselfT_lo; idx = i;
    } else if (i < 32768u) {
        unsigned ii = i - 16384u, j = ii >> 7, d = ii & 127u;
        v = Wclu[d * 128 + j]; hi = WcluT_hi; lo = WcluT_lo; idx = ii;
    } else if (i < 98304u) {
        unsigned ii = i - 32768u, j = ii >> 8, d = ii & 255u;
        v = Wf1[d * 256 + j]; hi = Wf1T_hi; lo = Wf1T_lo; idx = ii;
    } else {
        unsigned ii = i - 98304u, j = ii >> 8, d = ii & 255u;
        v = Wf2[d * 128 + j]; hi = Wf2T_hi; lo = Wf2T_lo; idx = ii;
    }
    short h = f2bs(v);
    hi[idx] = h;
    lo[idx] = f2bs(v - bs2f(h));
}

// ---------------- bucket edges; lists store packed (index, weight) ----------------
__global__ void k_bucket(
    const int* __restrict__ edge_pid, const int* __restrict__ edge_hid,
    const float* __restrict__ edge_w,
    int* __restrict__ cnt_he, int* __restrict__ cnt_p,
    int2* __restrict__ list_he, int2* __restrict__ list_p,
    int* __restrict__ ovf_he, int* __restrict__ ovf_he_cnt,
    int* __restrict__ ovf_p,  int* __restrict__ ovf_p_cnt) {
    unsigned e = blockIdx.x * blockDim.x + threadIdx.x;
    unsigned stride = gridDim.x * blockDim.x;
    for (; e < N_E; e += stride) {
        int h = edge_hid[e], p = edge_pid[e];
        int wbits = __float_as_int(edge_w[e]);
        int pos = atomicAdd(cnt_he + h, 1);
        if (pos < CAP_HE) list_he[h * CAP_HE + pos] = make_int2(p, wbits);
        else              ovf_he[atomicAdd(ovf_he_cnt, 1)] = (int)e;
        int pp = atomicAdd(cnt_p + p, 1);
        if (pp < CAP_P)   list_p[p * CAP_P + pp] = make_int2(h, wbits);
        else              ovf_p[atomicAdd(ovf_p_cnt, 1)] = (int)e;
    }
}

// ---------------- fused gather + attention per hyperedge ----------------
__global__ void k_he(
    const float* __restrict__ feat,
    const int* __restrict__ cnt_he, const int2* __restrict__ list_he,
    const int* __restrict__ ovf_he, const int* __restrict__ ovf_he_cnt,
    const float* __restrict__ edge_w,
    const int* __restrict__ edge_pid, const int* __restrict__ edge_hid,
    const float* __restrict__ Wh1, const float* __restrict__ bh1,
    const float* __restrict__ Wh2, const float* __restrict__ bh2,
    const float* __restrict__ Wfuse,
    float* __restrict__ he_weighted) {
    __shared__ float hef[D_IN];
    __shared__ float tmp[D_IN];
    __shared__ float attnv[N_HEADS];
    __shared__ float heattn;
    int h = blockIdx.x;
    int t = threadIdx.x;
    int half = t >> 7, d = t & 127;

    int n = cnt_he[h]; if (n > CAP_HE) n = CAP_HE;
    const int2* lst = list_he + (size_t)h * CAP_HE;
    float acc = 0.f;
    #pragma unroll 4
    for (int k = half; k < n; k += 2) {
        int2 pr = lst[k];
        acc += feat[(unsigned)pr.x * D_IN + d] * __int_as_float(pr.y);
    }
    int oc = *ovf_he_cnt;
    for (int k = half; k < oc; k += 2) {
        int e = ovf_he[k];
        if (edge_hid[e] == h)
            acc += feat[(unsigned)edge_pid[e] * D_IN + d] * edge_w[e];
    }
    if (half == 1) tmp[d] = acc;
    __syncthreads();
    if (half == 0) hef[d] = acc + tmp[d];
    __syncthreads();

    int head = t >> 6, k = t & 63;
    float s = bh1[head * HEAD_DIM + k];
    for (int dd = 0; dd < D_IN; ++dd)
        s += hef[dd] * Wh1[(head * D_IN + dd) * HEAD_DIM + k];
    s = fmaxf(s, 0.f);
    float val = s * Wh2[head * HEAD_DIM + k];
    for (int off = 32; off; off >>= 1) val += __shfl_down(val, off);
    if (k == 0) {
        float x = val + bh2[head];
        attnv[head] = 1.f / (1.f + expf(-x));
    }
    __syncthreads();
    if (t == 0) {
        float ha = 0.f;
        #pragma unroll
        for (int hh = 0; hh < N_HEADS; ++hh) ha += attnv[hh] * Wfuse[hh];
        heattn = ha;
    }
    __syncthreads();
    if (t < D_IN) he_weighted[h * D_IN + t] = hef[t] * heattn;
}

// ---------------- cluster gather: 2 proteins per 256-thread block ----------------
__global__ void k_gather_clu(
    const float* __restrict__ he_weighted,
    const int* __restrict__ cnt_p, const int2* __restrict__ list_p,
    const int* __restrict__ ovf_p, const int* __restrict__ ovf_p_cnt,
    const float* __restrict__ edge_w,
    const int* __restrict__ edge_pid, const int* __restrict__ edge_hid,
    float* __restrict__ cluster_feat) {
    int p = blockIdx.x * 2 + (threadIdx.x >> 7);
    int d = threadIdx.x & 127;
    int n = cnt_p[p]; if (n > CAP_P) n = CAP_P;
    const int2* lst = list_p + (size_t)p * CAP_P;
    float acc = 0.f;
    #pragma unroll 4
    for (int k = 0; k < n; ++k) {
        int2 pr = lst[k];
        acc += he_weighted[(unsigned)pr.x * D_IN + d] * __int_as_float(pr.y);
    }
    int oc = *ovf_p_cnt;
    for (int k = 0; k < oc; ++k) {
        int e = ovf_p[k];
        if (edge_pid[e] == p)
            acc += he_weighted[(unsigned)edge_hid[e] * D_IN + d] * edge_w[e];
    }
    cluster_feat[p * D_IN + d] = acc;
}

// ---------------- MLP stage 1: cat = [feat@Wself+b | clu@Wclu+b] -> global hi/lo ----------------
__global__ __launch_bounds__(256, 2) void k_mlp1(
    const float* __restrict__ feat, const float* __restrict__ cluster_feat,
    const short* __restrict__ WselfT_hi, const short* __restrict__ WselfT_lo, const float* __restrict__ bself,
    const short* __restrict__ WcluT_hi,  const short* __restrict__ WcluT_lo,  const float* __restrict__ bclu,
    short* __restrict__ catH, short* __restrict__ catL) {
    int t = threadIdx.x;
    int wv = t >> 6, lane = t & 63, col = lane & 15, q = lane >> 4;
    int m0 = blockIdx.x * 64;
    int tiles = NTILE_TOT - blockIdx.x * 4; if (tiles > 4) tiles = 4;
    const float* A = (wv < 2) ? feat : cluster_feat;
    const short* bHi = (wv < 2) ? WselfT_hi : WcluT_hi;
    const short* bLo = (wv < 2) ? WselfT_lo : WcluT_lo;
    const float* bias = (wv < 2) ? bself : bclu;
    int nb = (wv & 1) * 64;
    int cofs = (wv < 2) ? 0 : 128;

    short8 Bh[4][4], Bl[4][4];
    float bv[4];
    #pragma unroll
    for (int i = 0; i < 4; ++i) {
        int n = nb + i * 16 + col;
        bv[i] = bias[n];
        #pragma unroll
        for (int ks = 0; ks < 4; ++ks) {
            int kb = ks * 32 + q * 8;
            Bh[i][ks] = *(const short8*)&bHi[n * 128 + kb];
            Bl[i][ks] = *(const short8*)&bLo[n * 128 + kb];
        }
    }
    for (int mt = 0; mt < tiles; ++mt) {
        int row = m0 + mt * 16 + col;
        f32x4 acc[4];
        #pragma unroll
        for (int i = 0; i < 4; ++i) acc[i] = (f32x4){0.f, 0.f, 0.f, 0.f};
        #pragma unroll
        for (int ks = 0; ks < 4; ++ks) {
            int kb = ks * 32 + q * 8;
            const float* ap = A + (size_t)row * D_IN + kb;
            float4 a0 = *(const float4*)ap, a1 = *(const float4*)(ap + 4);
            float av[8] = {a0.x, a0.y, a0.z, a0.w, a1.x, a1.y, a1.z, a1.w};
            short8 ah, al;
            #pragma unroll
            for (int j = 0; j < 8; ++j) {
                short h = f2bs(av[j]); ah[j] = h; al[j] = f2bs(av[j] - bs2f(h));
            }
            #pragma unroll
            for (int i = 0; i < 4; ++i) {
                acc[i] = __builtin_amdgcn_mfma_f32_16x16x32_bf16(ah, Bh[i][ks], acc[i], 0, 0, 0);
                acc[i] = __builtin_amdgcn_mfma_f32_16x16x32_bf16(al, Bh[i][ks], acc[i], 0, 0, 0);
                acc[i] = __builtin_amdgcn_mfma_f32_16x16x32_bf16(ah, Bl[i][ks], acc[i], 0, 0, 0);
            }
        }
        #pragma unroll
        for (int i = 0; i < 4; ++i) {
            int n = nb + i * 16 + col;
            #pragma unroll
            for (int r = 0; r < 4; ++r) {
                float v = acc[i][r] + bv[i];
                short h = f2bs(v);
                size_t o = (size_t)(m0 + mt * 16 + q * 4 + r) * 256 + cofs + n;
                catH[o] = h;
                catL[o] = f2bs(v - bs2f(h));
            }
        }
    }
}

// ---------------- MLP stages 2+3: M=32/block for 4 blocks/CU occupancy ----------------
__global__ __launch_bounds__(256, 4) void k_mlp23(
    const short* __restrict__ catH, const short* __restrict__ catL,
    const short* __restrict__ Wf1T_hi, const short* __restrict__ Wf1T_lo, const float* __restrict__ bf1,
    const short* __restrict__ Wf2T_hi, const short* __restrict__ Wf2T_lo, const float* __restrict__ bf2,
    const float* __restrict__ Wf3, const float* __restrict__ bf3,
    const float* __restrict__ feat, float* __restrict__ out) {
    __shared__ __align__(16) short h1Hs[32 * CS2];   // 16.9 KB
    __shared__ __align__(16) short h1Ls[32 * CS2];   // 16.9 KB
    __shared__ float fw[32 * 2];
    float* h2F = (float*)h1Hs;       // alias: h1 dead before h2 written (sync-guarded)
    int t = threadIdx.x;
    int wv = t >> 6, lane = t & 63, col = lane & 15, q = lane >> 4;
    int m0 = blockIdx.x * 32;
    int tiles = NTILE_TOT - blockIdx.x * 2; if (tiles > 2) tiles = 2;
    int rows = tiles * 16;

    // ---- stage C: h1 = relu(cat @ Wf1 + bf1); wave n-slice 64, 2 passes of 2 n-subtiles ----
    for (int ih = 0; ih < 2; ++ih) {
        short8 Bh[2][8], Bl[2][8];
        #pragma unroll
        for (int ii = 0; ii < 2; ++ii) {
            int n = wv * 64 + (ih * 2 + ii) * 16 + col;
            #pragma unroll
            for (int ks = 0; ks < 8; ++ks) {
                int kb = ks * 32 + q * 8;
                Bh[ii][ks] = *(const short8*)&Wf1T_hi[n * 256 + kb];
                Bl[ii][ks] = *(const short8*)&Wf1T_lo[n * 256 + kb];
            }
        }
        for (int mt = 0; mt < tiles; ++mt) {
            int row = m0 + mt * 16 + col;
            f32x4 acc[2];
            #pragma unroll
            for (int ii = 0; ii < 2; ++ii) acc[ii] = (f32x4){0.f, 0.f, 0.f, 0.f};
            #pragma unroll
            for (int ks = 0; ks < 8; ++ks) {
                int kb = ks * 32 + q * 8;
                short8 ah = *(const short8*)&catH[(size_t)row * 256 + kb];
                short8 al = *(const short8*)&catL[(size_t)row * 256 + kb];
                #pragma unroll
                for (int ii = 0; ii < 2; ++ii) {
                    acc[ii] = __builtin_amdgcn_mfma_f32_16x16x32_bf16(ah, Bh[ii][ks], acc[ii], 0, 0, 0);
                    acc[ii] = __builtin_amdgcn_mfma_f32_16x16x32_bf16(al, Bh[ii][ks], acc[ii], 0, 0, 0);
                    acc[ii] = __builtin_amdgcn_mfma_f32_16x16x32_bf16(ah, Bl[ii][ks], acc[ii], 0, 0, 0);
                }
            }
            #pragma unroll
            for (int ii = 0; ii < 2; ++ii) {
                int n = wv * 64 + (ih * 2 + ii) * 16 + col;
                float bvv = bf1[n];
                #pragma unroll
                for (int r = 0; r < 4; ++r) {
                    float v = fmaxf(acc[ii][r] + bvv, 0.f);
                    short h = f2bs(v);
                    int rl = mt * 16 + q * 4 + r;
                    h1Hs[rl * CS2 + n] = h;
                    h1Ls[rl * CS2 + n] = f2bs(v - bs2f(h));
                }
            }
        }
    }
    __syncthreads();

    // ---- stage D: h2 = relu(h1 @ Wf2 + bf2); wave n-slice 32; results in regs ----
    f32x4 acc2[2][2];
    #pragma unroll
    for (int ii = 0; ii < 2; ++ii)
        #pragma unroll
        for (int mt = 0; mt < 2; ++mt) acc2[ii][mt] = (f32x4){0.f, 0.f, 0.f, 0.f};
    for (int ii = 0; ii < 2; ++ii) {
        short8 Bh2[8], Bl2[8];
        int n = wv * 32 + ii * 16 + col;
        #pragma unroll
        for (int ks = 0; ks < 8; ++ks) {
            int kb = ks * 32 + q * 8;
            Bh2[ks] = *(const short8*)&Wf2T_hi[n * 256 + kb];
            Bl2[ks] = *(const short8*)&Wf2T_lo[n * 256 + kb];
        }
        for (int mt = 0; mt < tiles; ++mt) {
            #pragma unroll
            for (int ks = 0; ks < 8; ++ks) {
                int kb = ks * 32 + q * 8;
                short8 ah = *(const short8*)&h1Hs[(mt * 16 + col) * CS2 + kb];
                short8 al = *(const short8*)&h1Ls[(mt * 16 + col) * CS2 + kb];
                acc2[ii][mt] = __builtin_amdgcn_mfma_f32_16x16x32_bf16(ah, Bh2[ks], acc2[ii][mt], 0, 0, 0);
                acc2[ii][mt] = __builtin_amdgcn_mfma_f32_16x16x32_bf16(al, Bh2[ks], acc2[ii][mt], 0, 0, 0);
                acc2[ii][mt] = __builtin_amdgcn_mfma_f32_16x16x32_bf16(ah, Bl2[ks], acc2[ii][mt], 0, 0, 0);
            }
        }
    }
    __syncthreads();   // all h1 reads complete before h2F overwrites the aliased region

    #pragma unroll
    for (int ii = 0; ii < 2; ++ii) {
        int n = wv * 32 + ii * 16 + col;
        float bvv = bf2[n];
        for (int mt = 0; mt < tiles; ++mt) {
            #pragma unroll
            for (int r = 0; r < 4; ++r)
                h2F[(mt * 16 + q * 4 + r) * 132 + n] = fmaxf(acc2[ii][mt][r] + bvv, 0.f);
        }
    }
    __syncthreads();

    // ---- logits + softmax: 8 threads per protein row (32 rows x 8 = 256) ----
    {
        int p = t >> 3, c = t & 7;
        if (p < rows) {
            float s0 = 0.f, s1 = 0.f;
            for (int n = c * 16; n < c * 16 + 16; ++n) {
                float h = h2F[p * 132 + n];
                s0 += h * Wf3[n * 2 + 0];
                s1 += h * Wf3[n * 2 + 1];
            }
            #pragma unroll
            for (int off = 4; off; off >>= 1) {
                s0 += __shfl_down(s0, off, 8);
                s1 += __shfl_down(s1, off, 8);
            }
            if (c == 0) {
                float l0 = s0 + bf3[0], l1 = s1 + bf3[1];
                float m = fmaxf(l0, l1);
                float e0 = expf(l0 - m), e1 = expf(l1 - m);
                float inv = 1.f / (e0 + e1);
                fw[p * 2 + 0] = e0 * inv;
                fw[p * 2 + 1] = e1 * inv;
            }
        }
    }
    __syncthreads();

    // ---- fuse + residual + relu + store ----
    #pragma unroll
    for (int k = 0; k < 2; ++k) {
        int idx = t + k * 256;           // 0..511 over 32 rows x 16 j-groups
        int rl = idx >> 4;
        int j = (idx & 15) * 8;
        if (rl < rows) {
            size_t ro = (size_t)(m0 + rl);
            short8 sh = *(const short8*)&catH[ro * 256 + j];
            short8 sl = *(const short8*)&catL[ro * 256 + j];
            short8 ch = *(const short8*)&catH[ro * 256 + 128 + j];
            short8 cl = *(const short8*)&catL[ro * 256 + 128 + j];
            const float* fp = feat + ro * D_IN + j;
            float4 f0 = *(const float4*)fp, f1 = *(const float4*)(fp + 4);
            float fe[8] = {f0.x, f0.y, f0.z, f0.w, f1.x, f1.y, f1.z, f1.w};
            float w0 = fw[rl * 2 + 0], w1 = fw[rl * 2 + 1];
            float o[8];
            #pragma unroll
            for (int qq = 0; qq < 8; ++qq) {
                float self_f = bs2f(sh[qq]) + bs2f(sl[qq]);
                float clu_f  = bs2f(ch[qq]) + bs2f(cl[qq]);
                o[qq] = fmaxf(self_f * w0 + clu_f * w1 + fe[qq], 0.f);
            }
            float* ob = out + ro * D_IN + j;
            *(float4*)ob = make_float4(o[0], o[1], o[2], o[3]);
            *(float4*)(ob + 4) = make_float4(o[4], o[5], o[6], o[7]);
        }
    }
}

extern "C" void kernel_launch(void* const* d_in, const int* in_sizes, int n_in,
                              void* d_out, int out_size, void* d_ws, size_t ws_size,
                              hipStream_t stream) {
    (void)in_sizes; (void)n_in; (void)out_size; (void)ws_size;
    const float* feat   = (const float*)d_in[0];
    const float* edge_w = (const float*)d_in[1];
    const float* Wself  = (const float*)d_in[2];
    const float* bself  = (const float*)d_in[3];
    const float* Wclu   = (const float*)d_in[4];
    const float* bclu   = (const float*)d_in[5];
    const float* Wh1    = (const float*)d_in[6];
    const float* bh1    = (const float*)d_in[7];
    const float* Wh2    = (const float*)d_in[8];
    const float* bh2    = (const float*)d_in[9];
    const float* Wfuse  = (const float*)d_in[10];
    const float* Wf1    = (const float*)d_in[11];
    const float* bf1_   = (const float*)d_in[12];
    const float* Wf2    = (const float*)d_in[13];
    const float* bf2_   = (const float*)d_in[14];
    const float* Wf3    = (const float*)d_in[15];
    const float* bf3_   = (const float*)d_in[16];
    const int* edge_pid = (const int*)d_in[17];
    const int* edge_hid = (const int*)d_in[18];
    float* out = (float*)d_out;

    // ---- workspace carve-up ----
    float* he_feat      = (float*)d_ws;                         // 5000*128
    float* cluster_feat = he_feat + (size_t)N_HE * D_IN;        // 50000*128
    int2* list_he = (int2*)(cluster_feat + (size_t)N_P * D_IN); // 5000*CAP_HE
    int2* list_p  = list_he + (size_t)N_HE * CAP_HE;            // 50000*CAP_P
    int* cnt_he  = (int*)(list_p + (size_t)N_P * CAP_P);        // 5000
    int* cnt_p   = cnt_he + N_HE;                               // 50000
    int* ovf_he_cnt = cnt_p + N_P;                              // 1
    int* ovf_p_cnt  = ovf_he_cnt + 1;                           // 1
    int* ovf_he  = ovf_p_cnt + 1;                               // N_E
    int* ovf_p   = ovf_he + N_E;                                // N_E
    short* WselfT_hi = (short*)(ovf_p + N_E);                   // 128*128 each
    short* WselfT_lo = WselfT_hi + 128 * 128;
    short* WcluT_hi  = WselfT_lo + 128 * 128;
    short* WcluT_lo  = WcluT_hi + 128 * 128;
    short* Wf1T_hi   = WcluT_lo + 128 * 128;                    // 256*256 each
    short* Wf1T_lo   = Wf1T_hi + 256 * 256;
    short* Wf2T_hi   = Wf1T_lo + 256 * 256;                     // 128*256 each
    short* Wf2T_lo   = Wf2T_hi + 128 * 256;
    short* catH      = Wf2T_lo + 128 * 256;                     // 50000*256
    short* catL      = catH + (size_t)N_P * 256;                // 50000*256

    k_prep<<<512, 256, 0, stream>>>(Wself, Wclu, Wf1, Wf2,
                                    WselfT_hi, WselfT_lo, WcluT_hi, WcluT_lo,
                                    Wf1T_hi, Wf1T_lo, Wf2T_hi, Wf2T_lo);
    k_zero_int<<<64, 256, 0, stream>>>(cnt_he, (unsigned)(N_HE + N_P + 2));
    k_bucket<<<2048, 256, 0, stream>>>(edge_pid, edge_hid, edge_w, cnt_he, cnt_p,
                                       list_he, list_p, ovf_he, ovf_he_cnt, ovf_p, ovf_p_cnt);
    k_he<<<N_HE, 256, 0, stream>>>(feat, cnt_he, list_he, ovf_he, ovf_he_cnt,
                                   edge_w, edge_pid, edge_hid,
                                   Wh1, bh1, Wh2, bh2, Wfuse, he_feat);
    k_gather_clu<<<N_P / 2, 256, 0, stream>>>(he_feat, cnt_p, list_p, ovf_p, ovf_p_cnt,
                                              edge_w, edge_pid, edge_hid, cluster_feat);
    k_mlp1<<<NCHUNK1, 256, 0, stream>>>(feat, cluster_feat,
                                        WselfT_hi, WselfT_lo, bself,
                                        WcluT_hi, WcluT_lo, bclu, catH, catL);
    k_mlp23<<<NCHUNK2, 256, 0, stream>>>(catH, catL,
                                         Wf1T_hi, Wf1T_lo, bf1_,
                                         Wf2T_hi, Wf2T_lo, bf2_,
                                         Wf3, bf3_, feat, out);
}

// Round 14
// 472.606 us; speedup vs baseline: 1.1859x; 1.1859x over previous
//
#include <hip/hip_runtime.h>

#define N_P 50000
#define N_HE 5000
#define N_E 800000
#define D_IN 128
#define D_HID 256
#define N_HEADS 4
#define HEAD_DIM 64
#define CAP_HE 320
#define CAP_P  64
#define NTILE_TOT 3125   // 50000 / 16
#define NCHUNK 782       // ceil(3125 / 4) chunks of 64 rows
#define CS2 264          // LDS stride (shorts) for h1

typedef __attribute__((ext_vector_type(8))) short short8;
typedef __attribute__((ext_vector_type(4))) float f32x4;

__device__ __forceinline__ short f2bs(float x) {   // fp32 -> bf16 bits (RNE)
    union { float f; unsigned u; } v; v.f = x;
    unsigned r = (v.u + 0x7FFFu + ((v.u >> 16) & 1u)) >> 16;
    return (short)r;
}
__device__ __forceinline__ float bs2f(short s) {
    union { unsigned u; float f; } v; v.u = ((unsigned)(unsigned short)s) << 16;
    return v.f;
}

__global__ void k_zero_int(int* __restrict__ p, unsigned n) {
    unsigned i = blockIdx.x * blockDim.x + threadIdx.x;
    unsigned stride = gridDim.x * blockDim.x;
    for (; i < n; i += stride) p[i] = 0;
}

// ---------------- weight prep: fp32 -> split bf16 (hi+lo), transposed WT[n][k] ----------------
__global__ void k_prep(
    const float* __restrict__ Wself, const float* __restrict__ Wclu,
    const float* __restrict__ Wf1,   const float* __restrict__ Wf2,
    short* __restrict__ WselfT_hi, short* __restrict__ WselfT_lo,
    short* __restrict__ WcluT_hi,  short* __restrict__ WcluT_lo,
    short* __restrict__ Wf1T_hi,   short* __restrict__ Wf1T_lo,
    short* __restrict__ Wf2T_hi,   short* __restrict__ Wf2T_lo) {
    unsigned i = blockIdx.x * 256u + threadIdx.x;   // 512*256 = 131072 exact
    float v; short *hi, *lo; unsigned idx;
    if (i < 16384u) {
        unsigned j = i >> 7, d = i & 127u;
        v = Wself[d * 128 + j]; hi = WselfT_hi; lo = WselfT_lo; idx = i;
    } else if (i < 32768u) {
        unsigned ii = i - 16384u, j = ii >> 7, d = ii & 127u;
        v = Wclu[d * 128 + j]; hi = WcluT_hi; lo = WcluT_lo; idx = ii;
    } else if (i < 98304u) {
        unsigned ii = i - 32768u, j = ii >> 8, d = ii & 255u;
        v = Wf1[d * 256 + j]; hi = Wf1T_hi; lo = Wf1T_lo; idx = ii;
    } else {
        unsigned ii = i - 98304u, j = ii >> 8, d = ii & 255u;
        v = Wf2[d * 128 + j]; hi = Wf2T_hi; lo = Wf2T_lo; idx = ii;
    }
    short h = f2bs(v);
    hi[idx] = h;
    lo[idx] = f2bs(v - bs2f(h));
}

// ---------------- bucket edges; lists store packed (index, weight) ----------------
__global__ void k_bucket(
    const int* __restrict__ edge_pid, const int* __restrict__ edge_hid,
    const float* __restrict__ edge_w,
    int* __restrict__ cnt_he, int* __restrict__ cnt_p,
    int2* __restrict__ list_he, int2* __restrict__ list_p,
    int* __restrict__ ovf_he, int* __restrict__ ovf_he_cnt,
    int* __restrict__ ovf_p,  int* __restrict__ ovf_p_cnt) {
    unsigned e = blockIdx.x * blockDim.x + threadIdx.x;
    unsigned stride = gridDim.x * blockDim.x;
    for (; e < N_E; e += stride) {
        int h = edge_hid[e], p = edge_pid[e];
        int wbits = __float_as_int(edge_w[e]);
        int pos = atomicAdd(cnt_he + h, 1);
        if (pos < CAP_HE) list_he[h * CAP_HE + pos] = make_int2(p, wbits);
        else              ovf_he[atomicAdd(ovf_he_cnt, 1)] = (int)e;
        int pp = atomicAdd(cnt_p + p, 1);
        if (pp < CAP_P)   list_p[p * CAP_P + pp] = make_int2(h, wbits);
        else              ovf_p[atomicAdd(ovf_p_cnt, 1)] = (int)e;
    }
}

// ---------------- fused gather + attention; 4-way K-split gather ----------------
// Each wave owns the full 128-dim row as float2 (64 lanes x 8 B, fully coalesced)
// and walks every 4th list entry -> sequential chain n/4 instead of n/2.
__global__ void k_he(
    const float* __restrict__ feat,
    const int* __restrict__ cnt_he, const int2* __restrict__ list_he,
    const int* __restrict__ ovf_he, const int* __restrict__ ovf_he_cnt,
    const float* __restrict__ edge_w,
    const int* __restrict__ edge_pid, const int* __restrict__ edge_hid,
    const float* __restrict__ Wh1, const float* __restrict__ bh1,
    const float* __restrict__ Wh2, const float* __restrict__ bh2,
    const float* __restrict__ Wfuse,
    float* __restrict__ he_weighted) {
    __shared__ float ptl[4][D_IN];     // per-wave partial rows
    __shared__ float hef[D_IN];
    __shared__ float attnv[N_HEADS];
    __shared__ float heattn;
    int h = blockIdx.x;
    int t = threadIdx.x;
    int wv = t >> 6, lane = t & 63;

    int n = cnt_he[h]; if (n > CAP_HE) n = CAP_HE;
    const int2* lst = list_he + (size_t)h * CAP_HE;
    float2 acc = make_float2(0.f, 0.f);
    #pragma unroll 4
    for (int k = wv; k < n; k += 4) {
        int2 pr = lst[k];               // broadcast within wave
        float2 f = *(const float2*)(feat + (size_t)(unsigned)pr.x * D_IN + lane * 2);
        float w = __int_as_float(pr.y);
        acc.x += f.x * w; acc.y += f.y * w;
    }
    int oc = *ovf_he_cnt;               // normally 0
    for (int k = wv; k < oc; k += 4) {
        int e = ovf_he[k];
        if (edge_hid[e] == h) {
            float2 f = *(const float2*)(feat + (size_t)(unsigned)edge_pid[e] * D_IN + lane * 2);
            float w = edge_w[e];
            acc.x += f.x * w; acc.y += f.y * w;
        }
    }
    ptl[wv][lane * 2] = acc.x;
    ptl[wv][lane * 2 + 1] = acc.y;
    __syncthreads();
    if (t < D_IN) hef[t] = ptl[0][t] + ptl[1][t] + ptl[2][t] + ptl[3][t];
    __syncthreads();

    int head = wv, k = lane;
    float s = bh1[head * HEAD_DIM + k];
    for (int dd = 0; dd < D_IN; ++dd)
        s += hef[dd] * Wh1[(head * D_IN + dd) * HEAD_DIM + k];
    s = fmaxf(s, 0.f);
    float val = s * Wh2[head * HEAD_DIM + k];
    for (int off = 32; off; off >>= 1) val += __shfl_down(val, off);
    if (k == 0) {
        float x = val + bh2[head];
        attnv[head] = 1.f / (1.f + expf(-x));
    }
    __syncthreads();
    if (t == 0) {
        float ha = 0.f;
        #pragma unroll
        for (int hh = 0; hh < N_HEADS; ++hh) ha += attnv[hh] * Wfuse[hh];
        heattn = ha;
    }
    __syncthreads();
    if (t < D_IN) he_weighted[h * D_IN + t] = hef[t] * heattn;
}

// ---------------- cluster gather (R12 config: 1 protein / 128-thread block) ----------------
__global__ void k_gather_clu(
    const float* __restrict__ he_weighted,
    const int* __restrict__ cnt_p, const int2* __restrict__ list_p,
    const int* __restrict__ ovf_p, const int* __restrict__ ovf_p_cnt,
    const float* __restrict__ edge_w,
    const int* __restrict__ edge_pid, const int* __restrict__ edge_hid,
    float* __restrict__ cluster_feat) {
    int p = blockIdx.x;
    int n = cnt_p[p]; if (n > CAP_P) n = CAP_P;
    const int2* lst = list_p + (size_t)p * CAP_P;
    int d = threadIdx.x;
    float acc = 0.f;
    #pragma unroll 4
    for (int k = 0; k < n; ++k) {
        int2 pr = lst[k];
        acc += he_weighted[(unsigned)pr.x * D_IN + d] * __int_as_float(pr.y);
    }
    int oc = *ovf_p_cnt;
    for (int k = 0; k < oc; ++k) {
        int e = ovf_p[k];
        if (edge_pid[e] == p)
            acc += he_weighted[(unsigned)edge_hid[e] * D_IN + d] * edge_w[e];
    }
    cluster_feat[p * D_IN + d] = acc;
}

// ---------------- MLP stage 1: cat = [feat@Wself+b | clu@Wclu+b] -> global hi/lo ----------------
__global__ __launch_bounds__(256, 2) void k_mlp1(
    const float* __restrict__ feat, const float* __restrict__ cluster_feat,
    const short* __restrict__ WselfT_hi, const short* __restrict__ WselfT_lo, const float* __restrict__ bself,
    const short* __restrict__ WcluT_hi,  const short* __restrict__ WcluT_lo,  const float* __restrict__ bclu,
    short* __restrict__ catH, short* __restrict__ catL) {
    int t = threadIdx.x;
    int wv = t >> 6, lane = t & 63, col = lane & 15, q = lane >> 4;
    int m0 = blockIdx.x * 64;
    int tiles = NTILE_TOT - blockIdx.x * 4; if (tiles > 4) tiles = 4;
    const float* A = (wv < 2) ? feat : cluster_feat;
    const short* bHi = (wv < 2) ? WselfT_hi : WcluT_hi;
    const short* bLo = (wv < 2) ? WselfT_lo : WcluT_lo;
    const float* bias = (wv < 2) ? bself : bclu;
    int nb = (wv & 1) * 64;
    int cofs = (wv < 2) ? 0 : 128;

    short8 Bh[4][4], Bl[4][4];
    float bv[4];
    #pragma unroll
    for (int i = 0; i < 4; ++i) {
        int n = nb + i * 16 + col;
        bv[i] = bias[n];
        #pragma unroll
        for (int ks = 0; ks < 4; ++ks) {
            int kb = ks * 32 + q * 8;
            Bh[i][ks] = *(const short8*)&bHi[n * 128 + kb];
            Bl[i][ks] = *(const short8*)&bLo[n * 128 + kb];
        }
    }
    for (int mt = 0; mt < tiles; ++mt) {
        int row = m0 + mt * 16 + col;
        f32x4 acc[4];
        #pragma unroll
        for (int i = 0; i < 4; ++i) acc[i] = (f32x4){0.f, 0.f, 0.f, 0.f};
        #pragma unroll
        for (int ks = 0; ks < 4; ++ks) {
            int kb = ks * 32 + q * 8;
            const float* ap = A + (size_t)row * D_IN + kb;
            float4 a0 = *(const float4*)ap, a1 = *(const float4*)(ap + 4);
            float av[8] = {a0.x, a0.y, a0.z, a0.w, a1.x, a1.y, a1.z, a1.w};
            short8 ah, al;
            #pragma unroll
            for (int j = 0; j < 8; ++j) {
                short h = f2bs(av[j]); ah[j] = h; al[j] = f2bs(av[j] - bs2f(h));
            }
            #pragma unroll
            for (int i = 0; i < 4; ++i) {
                acc[i] = __builtin_amdgcn_mfma_f32_16x16x32_bf16(ah, Bh[i][ks], acc[i], 0, 0, 0);
                acc[i] = __builtin_amdgcn_mfma_f32_16x16x32_bf16(al, Bh[i][ks], acc[i], 0, 0, 0);
                acc[i] = __builtin_amdgcn_mfma_f32_16x16x32_bf16(ah, Bl[i][ks], acc[i], 0, 0, 0);
            }
        }
        #pragma unroll
        for (int i = 0; i < 4; ++i) {
            int n = nb + i * 16 + col;
            #pragma unroll
            for (int r = 0; r < 4; ++r) {
                float v = acc[i][r] + bv[i];
                short h = f2bs(v);
                size_t o = (size_t)(m0 + mt * 16 + q * 4 + r) * 256 + cofs + n;
                catH[o] = h;
                catL[o] = f2bs(v - bs2f(h));
            }
        }
    }
}

// ---------------- MLP stages 2+3 (R12 config: M=64/block) ----------------
__global__ __launch_bounds__(256, 2) void k_mlp23(
    const short* __restrict__ catH, const short* __restrict__ catL,
    const short* __restrict__ Wf1T_hi, const short* __restrict__ Wf1T_lo, const float* __restrict__ bf1,
    const short* __restrict__ Wf2T_hi, const short* __restrict__ Wf2T_lo, const float* __restrict__ bf2,
    const float* __restrict__ Wf3, const float* __restrict__ bf3,
    const float* __restrict__ feat, float* __restrict__ out) {
    __shared__ __align__(16) short h1Hs[64 * CS2];   // 33.8 KB
    __shared__ __align__(16) short h1Ls[64 * CS2];   // 33.8 KB
    __shared__ float fw[64 * 2];
    float* h2F = (float*)h1Hs;       // alias: h1 dead before h2 written (sync-guarded)
    int t = threadIdx.x;
    int wv = t >> 6, lane = t & 63, col = lane & 15, q = lane >> 4;
    int m0 = blockIdx.x * 64;
    int tiles = NTILE_TOT - blockIdx.x * 4; if (tiles > 4) tiles = 4;
    int rows = tiles * 16;

    // ---- stage C: h1 = relu(cat @ Wf1 + bf1) ----
    for (int ih = 0; ih < 2; ++ih) {
        short8 Bh[2][8], Bl[2][8];
        #pragma unroll
        for (int ii = 0; ii < 2; ++ii) {
            int n = wv * 64 + (ih * 2 + ii) * 16 + col;
            #pragma unroll
            for (int ks = 0; ks < 8; ++ks) {
                int kb = ks * 32 + q * 8;
                Bh[ii][ks] = *(const short8*)&Wf1T_hi[n * 256 + kb];
                Bl[ii][ks] = *(const short8*)&Wf1T_lo[n * 256 + kb];
            }
        }
        for (int mt = 0; mt < tiles; ++mt) {
            int row = m0 + mt * 16 + col;
            f32x4 acc[2];
            #pragma unroll
            for (int ii = 0; ii < 2; ++ii) acc[ii] = (f32x4){0.f, 0.f, 0.f, 0.f};
            #pragma unroll
            for (int ks = 0; ks < 8; ++ks) {
                int kb = ks * 32 + q * 8;
                short8 ah = *(const short8*)&catH[(size_t)row * 256 + kb];
                short8 al = *(const short8*)&catL[(size_t)row * 256 + kb];
                #pragma unroll
                for (int ii = 0; ii < 2; ++ii) {
                    acc[ii] = __builtin_amdgcn_mfma_f32_16x16x32_bf16(ah, Bh[ii][ks], acc[ii], 0, 0, 0);
                    acc[ii] = __builtin_amdgcn_mfma_f32_16x16x32_bf16(al, Bh[ii][ks], acc[ii], 0, 0, 0);
                    acc[ii] = __builtin_amdgcn_mfma_f32_16x16x32_bf16(ah, Bl[ii][ks], acc[ii], 0, 0, 0);
                }
            }
            #pragma unroll
            for (int ii = 0; ii < 2; ++ii) {
                int n = wv * 64 + (ih * 2 + ii) * 16 + col;
                float bvv = bf1[n];
                #pragma unroll
                for (int r = 0; r < 4; ++r) {
                    float v = fmaxf(acc[ii][r] + bvv, 0.f);
                    short h = f2bs(v);
                    int rl = mt * 16 + q * 4 + r;
                    h1Hs[rl * CS2 + n] = h;
                    h1Ls[rl * CS2 + n] = f2bs(v - bs2f(h));
                }
            }
        }
    }
    __syncthreads();

    // ---- stage D: h2 = relu(h1 @ Wf2 + bf2); results in regs ----
    f32x4 acc2[2][4];
    #pragma unroll
    for (int ii = 0; ii < 2; ++ii)
        #pragma unroll
        for (int mt = 0; mt < 4; ++mt) acc2[ii][mt] = (f32x4){0.f, 0.f, 0.f, 0.f};
    for (int ii = 0; ii < 2; ++ii) {
        short8 Bh2[8], Bl2[8];
        int n = wv * 32 + ii * 16 + col;
        #pragma unroll
        for (int ks = 0; ks < 8; ++ks) {
            int kb = ks * 32 + q * 8;
            Bh2[ks] = *(const short8*)&Wf2T_hi[n * 256 + kb];
            Bl2[ks] = *(const short8*)&Wf2T_lo[n * 256 + kb];
        }
        for (int mt = 0; mt < tiles; ++mt) {
            #pragma unroll
            for (int ks = 0; ks < 8; ++ks) {
                int kb = ks * 32 + q * 8;
                short8 ah = *(const short8*)&h1Hs[(mt * 16 + col) * CS2 + kb];
                short8 al = *(const short8*)&h1Ls[(mt * 16 + col) * CS2 + kb];
                acc2[ii][mt] = __builtin_amdgcn_mfma_f32_16x16x32_bf16(ah, Bh2[ks], acc2[ii][mt], 0, 0, 0);
                acc2[ii][mt] = __builtin_amdgcn_mfma_f32_16x16x32_bf16(al, Bh2[ks], acc2[ii][mt], 0, 0, 0);
                acc2[ii][mt] = __builtin_amdgcn_mfma_f32_16x16x32_bf16(ah, Bl2[ks], acc2[ii][mt], 0, 0, 0);
            }
        }
    }
    __syncthreads();   // all h1 reads complete before h2F overwrites the aliased region

    #pragma unroll
    for (int ii = 0; ii < 2; ++ii) {
        int n = wv * 32 + ii * 16 + col;
        float bvv = bf2[n];
        for (int mt = 0; mt < tiles; ++mt) {
            #pragma unroll
            for (int r = 0; r < 4; ++r)
                h2F[(mt * 16 + q * 4 + r) * 132 + n] = fmaxf(acc2[ii][mt][r] + bvv, 0.f);
        }
    }
    __syncthreads();

    // ---- logits + softmax: 4 threads per protein row ----
    {
        int p = t >> 2, c = t & 3;
        if (p < rows) {
            float s0 = 0.f, s1 = 0.f;
            for (int n = c * 32; n < c * 32 + 32; ++n) {
                float h = h2F[p * 132 + n];
                s0 += h * Wf3[n * 2 + 0];
                s1 += h * Wf3[n * 2 + 1];
            }
            #pragma unroll
            for (int off = 2; off; off >>= 1) {
                s0 += __shfl_down(s0, off, 4);
                s1 += __shfl_down(s1, off, 4);
            }
            if (c == 0) {
                float l0 = s0 + bf3[0], l1 = s1 + bf3[1];
                float m = fmaxf(l0, l1);
                float e0 = expf(l0 - m), e1 = expf(l1 - m);
                float inv = 1.f / (e0 + e1);
                fw[p * 2 + 0] = e0 * inv;
                fw[p * 2 + 1] = e1 * inv;
            }
        }
    }
    __syncthreads();

    // ---- fuse + residual + relu + store ----
    #pragma unroll
    for (int k = 0; k < 4; ++k) {
        int idx = t + k * 256;           // 0..1023 over 64 rows x 16 j-groups
        int rl = idx >> 4;
        int j = (idx & 15) * 8;
        if (rl < rows) {
            size_t ro = (size_t)(m0 + rl);
            short8 sh = *(const short8*)&catH[ro * 256 + j];
            short8 sl = *(const short8*)&catL[ro * 256 + j];
            short8 ch = *(const short8*)&catH[ro * 256 + 128 + j];
            short8 cl = *(const short8*)&catL[ro * 256 + 128 + j];
            const float* fp = feat + ro * D_IN + j;
            float4 f0 = *(const float4*)fp, f1 = *(const float4*)(fp + 4);
            float fe[8] = {f0.x, f0.y, f0.z, f0.w, f1.x, f1.y, f1.z, f1.w};
            float w0 = fw[rl * 2 + 0], w1 = fw[rl * 2 + 1];
            float o[8];
            #pragma unroll
            for (int qq = 0; qq < 8; ++qq) {
                float self_f = bs2f(sh[qq]) + bs2f(sl[qq]);
                float clu_f  = bs2f(ch[qq]) + bs2f(cl[qq]);
                o[qq] = fmaxf(self_f * w0 + clu_f * w1 + fe[qq], 0.f);
            }
            float* ob = out + ro * D_IN + j;
            *(float4*)ob = make_float4(o[0], o[1], o[2], o[3]);
            *(float4*)(ob + 4) = make_float4(o[4], o[5], o[6], o[7]);
        }
    }
}

extern "C" void kernel_launch(void* const* d_in, const int* in_sizes, int n_in,
                              void* d_out, int out_size, void* d_ws, size_t ws_size,
                              hipStream_t stream) {
    (void)in_sizes; (void)n_in; (void)out_size; (void)ws_size;
    const float* feat   = (const float*)d_in[0];
    const float* edge_w = (const float*)d_in[1];
    const float* Wself  = (const float*)d_in[2];
    const float* bself  = (const float*)d_in[3];
    const float* Wclu   = (const float*)d_in[4];
    const float* bclu   = (const float*)d_in[5];
    const float* Wh1    = (const float*)d_in[6];
    const float* bh1    = (const float*)d_in[7];
    const float* Wh2    = (const float*)d_in[8];
    const float* bh2    = (const float*)d_in[9];
    const float* Wfuse  = (const float*)d_in[10];
    const float* Wf1    = (const float*)d_in[11];
    const float* bf1_   = (const float*)d_in[12];
    const float* Wf2    = (const float*)d_in[13];
    const float* bf2_   = (const float*)d_in[14];
    const float* Wf3    = (const float*)d_in[15];
    const float* bf3_   = (const float*)d_in[16];
    const int* edge_pid = (const int*)d_in[17];
    const int* edge_hid = (const int*)d_in[18];
    float* out = (float*)d_out;

    // ---- workspace carve-up ----
    float* he_feat      = (float*)d_ws;                         // 5000*128
    float* cluster_feat = he_feat + (size_t)N_HE * D_IN;        // 50000*128
    int2* list_he = (int2*)(cluster_feat + (size_t)N_P * D_IN); // 5000*CAP_HE
    int2* list_p  = list_he + (size_t)N_HE * CAP_HE;            // 50000*CAP_P
    int* cnt_he  = (int*)(list_p + (size_t)N_P * CAP_P);        // 5000
    int* cnt_p   = cnt_he + N_HE;                               // 50000
    int* ovf_he_cnt = cnt_p + N_P;                              // 1
    int* ovf_p_cnt  = ovf_he_cnt + 1;                           // 1
    int* ovf_he  = ovf_p_cnt + 1;                               // N_E
    int* ovf_p   = ovf_he + N_E;                                // N_E
    short* WselfT_hi = (short*)(ovf_p + N_E);                   // 128*128 each
    short* WselfT_lo = WselfT_hi + 128 * 128;
    short* WcluT_hi  = WselfT_lo + 128 * 128;
    short* WcluT_lo  = WcluT_hi + 128 * 128;
    short* Wf1T_hi   = WcluT_lo + 128 * 128;                    // 256*256 each
    short* Wf1T_lo   = Wf1T_hi + 256 * 256;
    short* Wf2T_hi   = Wf1T_lo + 256 * 256;                     // 128*256 each
    short* Wf2T_lo   = Wf2T_hi + 128 * 256;
    short* catH      = Wf2T_lo + 128 * 256;                     // 50000*256
    short* catL      = catH + (size_t)N_P * 256;                // 50000*256

    k_prep<<<512, 256, 0, stream>>>(Wself, Wclu, Wf1, Wf2,
                                    WselfT_hi, WselfT_lo, WcluT_hi, WcluT_lo,
                                    Wf1T_hi, Wf1T_lo, Wf2T_hi, Wf2T_lo);
    k_zero_int<<<64, 256, 0, stream>>>(cnt_he, (unsigned)(N_HE + N_P + 2));
    k_bucket<<<2048, 256, 0, stream>>>(edge_pid, edge_hid, edge_w, cnt_he, cnt_p,
                                       list_he, list_p, ovf_he, ovf_he_cnt, ovf_p, ovf_p_cnt);
    k_he<<<N_HE, 256, 0, stream>>>(feat, cnt_he, list_he, ovf_he, ovf_he_cnt,
                                   edge_w, edge_pid, edge_hid,
                                   Wh1, bh1, Wh2, bh2, Wfuse, he_feat);
    k_gather_clu<<<N_P, 128, 0, stream>>>(he_feat, cnt_p, list_p, ovf_p, ovf_p_cnt,
                                          edge_w, edge_pid, edge_hid, cluster_feat);
    k_mlp1<<<NCHUNK, 256, 0, stream>>>(feat, cluster_feat,
                                       WselfT_hi, WselfT_lo, bself,
                                       WcluT_hi, WcluT_lo, bclu, catH, catL);
    k_mlp23<<<NCHUNK, 256, 0, stream>>>(catH, catL,
                                        Wf1T_hi, Wf1T_lo, bf1_,
                                        Wf2T_hi, Wf2T_lo, bf2_,
                                        Wf3, bf3_, feat, out);
}